// Round 2
// baseline (98.793 us; speedup 1.0000x reference)
//
#include <hip/hip_runtime.h>
#include <math.h>

#define HW 1024
#define NB 16
#define TMAXS 1024

typedef unsigned long long ull;

__device__ __forceinline__ double u2d(ull u) {
  return __longlong_as_double((long long)u);
}
__device__ __forceinline__ ull d2u(double d) {
  return (ull)__double_as_longlong(d);
}

// key = exp(-(0.5*g + 0.5*h)/sqrt(32)) with pre-halved operands (validated
// bit-exact vs reference in rounds 0-1: same op chain, contract off).
__device__ __forceinline__ float keyhalf(float gh, float hh) {
#pragma clang fp contract(off)
  const float INV = 0.17677669529663687f; // fl32(1/sqrt(32))
  return expf(-(gh + hh) * INV);
}

// One DPP reduction stage on packed-f64 (nonnegative; disabled lanes give
// 0.0 = identity). Chain validated in prior rounds.
template <int CTRL>
__device__ __forceinline__ double dpp_fmax64(double x) {
  ull u = d2u(x);
  int lo = (int)(unsigned)u;
  int hi = (int)(unsigned)(u >> 32);
  int lo2 = __builtin_amdgcn_update_dpp(0, lo, CTRL, 0xF, 0xF, false);
  int hi2 = __builtin_amdgcn_update_dpp(0, hi, CTRL, 0xF, 0xF, false);
  double y = u2d(((ull)(unsigned)hi2 << 32) | (unsigned)lo2);
  return fmax(x, y);
}

// Bank-skewed cell index: 16B structs at stride 16 put cells differing by 8
// in the same bank; skew-3 gives the 9 touched cells (sel + {-33..33}) eight
// distinct banks + one free 2-way alias.
__device__ __forceinline__ int skew(int c) { return c + 3 * (c >> 5); }

// ---------------------------------------------------------------------------
// Fused per-batch A* + backtrack, one wave per batch.
// R2: instruction-diet rebuild (loop measured mixed issue/latency bound):
//  - cell struct uint4 {g, cm, hw05, flg} in skewed LDS: ONE b128 read and
//    ONE merged b128 write per touched cell (was 3 reads/3 writes + addr).
//  - struct[sel] broadcast b128 -> g2full = g+cm per-lane (exact; 0.5*x and
//    2*(0.5*x) exact), no readlane, no separate z field (recompute proven
//    bit-identical to the stored-z of validated rounds).
//  - pop flg is the constant 5 (popped cell was open => free=1, hist=0).
//  - merged predicated DS: one struct write (pop lane 8 + relaxers), one
//    key2 write (denorm + pk), one group atomic (lanes 0..15), one relax
//    atomic.  Early-write order restored (R1 regression: late writes queue
//    ahead of next iter's reads in the in-order DS pipe).
//  - fold: prefold 6-stage over stale level1 (hidden in LDS window) -> MP
//    sgpr pair; late fold = group keys on lanes 0..15 (patched), fresh pk
//    fmax-merged into lanes 0..7, MP injected via one v_max_f64 -> 4-stage
//    row-0 fold -> ONE readlane.  Fold multiset identical to validated
//    rounds (max associative, ties impossible: distinct idx bits).
//  - neighbor validity via scalar mask (SALU cselects) instead of per-lane
//    row/col compares.
// ---------------------------------------------------------------------------
extern "C" __global__ void __launch_bounds__(64) astar_fused(
    const float* __restrict__ cm_g, const float* __restrict__ sm_g,
    const float* __restrict__ gm_g, const float* __restrict__ om_g,
    float* __restrict__ out) {
#pragma clang fp contract(off)
  const int b = blockIdx.x;
  const int lane = threadIdx.x;

  __shared__ __align__(16) uint4 cellT[1117]; // skewed {g, cm, hw05, flg}
  __shared__ __align__(16) ull key2[HW];      // packed (f64 key | 1023-idx)
  __shared__ __align__(16) unsigned par[HW];  // parent | mark bit31
  __shared__ __align__(16) ull level1[64];    // per-16-cell-group max

  const float* cm = cm_g + b * HW;
  const float* sm = sm_g + b * HW;
  const float* gm = gm_g + b * HW;
  const float* om = om_g + b * HW;

  // ---- init pass 1: vectorized loads, locate goal/start ----
  float4 c4[4], o4[4];
  int gi = -1, si = -1;
#pragma unroll
  for (int q = 0; q < 4; ++q) {
    const int base = q * 256 + lane * 4;
    c4[q] = *(const float4*)(cm + base);
    o4[q] = *(const float4*)(om + base);
    const float4 s4 = *(const float4*)(sm + base);
    const float4 g4 = *(const float4*)(gm + base);
    const float sv[4] = {s4.x, s4.y, s4.z, s4.w};
    const float gv[4] = {g4.x, g4.y, g4.z, g4.w};
#pragma unroll
    for (int j = 0; j < 4; ++j) {
      if (gv[j] > 0.5f) gi = base + j;
      if (sv[j] > 0.5f) si = base + j;
    }
  }
#pragma unroll
  for (int m = 32; m >= 1; m >>= 1) {
    const int og = __shfl_xor(gi, m, 64);
    const int os = __shfl_xor(si, m, 64);
    gi = (og > gi) ? og : gi;
    si = (os > si) ? os : si;
  }
  const int goal = __builtin_amdgcn_readfirstlane(gi);
  const int start = __builtin_amdgcn_readfirstlane(si);

  // ---- init pass 2: h (exact ref op order), cell structs, key2, level1 ----
  level1[lane] = 0ull;
  const float grf = (float)(goal >> 5), gcf = (float)(goal & 31);
#pragma unroll
  for (int q = 0; q < 4; ++q) {
    const int base = q * 256 + lane * 4;
    const float cv[4] = {c4[q].x, c4[q].y, c4[q].z, c4[q].w};
    const float ov[4] = {o4[q].x, o4[q].y, o4[q].z, o4[q].w};
    ull pk[4];
#pragma unroll
    for (int j = 0; j < 4; ++j) {
      const int cell = base + j;
      const float rr = (float)(cell >> 5), cc = (float)(cell & 31);
      const float dr = fabsf(rr - grf), dc = fabsf(cc - gcf);
      const float h0 = (dr + dc) - fminf(dr, dc); // exact (small ints)
      const float euc = sqrtf(dr * dr + dc * dc); // exact radicand
      const float t1 = 0.001f * euc;              // contract off: no fma
      const float hh = h0 + t1;
      const float hf = hh + cv[j]; // h_full (h + cm), exact ref order
      const float hw = 0.5f * hf;  // exact scaling
      unsigned fv = (ov[j] > 0.5f) ? 1u : 0u;
      pk[j] = (ull)(1023 - cell);
      if (cell == start) {
        fv |= 2u;
        pk[j] |= d2u((double)keyhalf(0.0f, hw));
      }
      cellT[skew(cell)] = make_uint4(__float_as_uint(0.0f),
                                     __float_as_uint(cv[j]),
                                     __float_as_uint(hw), fv);
      atomicMax(&level1[cell >> 4], pk[j]);
    }
    *(uint4*)&par[base] =
        make_uint4((unsigned)goal, (unsigned)goal, (unsigned)goal, (unsigned)goal);
    ulonglong2 k01, k23;
    k01.x = pk[0]; k01.y = pk[1];
    k23.x = pk[2]; k23.y = pk[3];
    *(ulonglong2*)&key2[base] = k01;
    *(ulonglong2*)&key2[base + 2] = k23;
  }
  __builtin_amdgcn_wave_barrier();
  ull stale = level1[lane]; // S_{-1} group maxes

  // per-lane neighbor offset (lanes 0..7), others garbage/unused
  int dlt = 0;
  {
    const int k = (lane < 4) ? lane : lane + 1; // skip center
    dlt = (k / 3 - 1) * 32 + (k % 3 - 1);
  }

  int sel = start;
  bool reached = false;

#pragma unroll 1
  for (int step = 0; step < TMAXS; ++step) {
    if (sel == goal) { reached = true; break; }
    const int gp = sel >> 4;
    const int sxsel = skew(sel);

    // scalar neighbor-validity mask (lanes: 0,1,2=top row; 0,3,5=left col;
    // 2,4,7=right col; 5,6,7=bottom row)
    const int sr = sel >> 5, sc = sel & 31;
    unsigned vmask = 0xFFu;
    if (sr == 0) vmask &= ~0x07u;
    if (sr == 31) vmask &= ~0xE0u;
    if (sc == 0) vmask &= ~0x29u;
    if (sc == 31) vmask &= ~0x94u;

    // -- DS phase: zero popped group's level1, then all reads --
    if (lane == 16) level1[gp] = 0ull;
    const uint4 sv = cellT[sxsel]; // broadcast: {g, cm, hw05, flg} of sel
    const int n = sel + dlt;
    const bool relaxer = (lane < 8) && ((vmask >> lane) & 1u);
    uint4 nv = make_uint4(0u, 0u, 0u, 0u);
    if (relaxer) nv = cellT[skew(n)];
    ull gco = 0ull;
    if (lane < 16) gco = key2[gp * 16 + lane];

    // -- prefold over stale level1 (covers all groups != gp); hidden in the
    //    LDS latency window --
    double mp = (lane == gp) ? 0.0 : u2d(stale);
    mp = dpp_fmax64<0x111>(mp);
    mp = dpp_fmax64<0x112>(mp);
    mp = dpp_fmax64<0x114>(mp);
    mp = dpp_fmax64<0x118>(mp);
    mp = dpp_fmax64<0x142>(mp);
    mp = dpp_fmax64<0x143>(mp);
    const ull mpb = d2u(mp);
    const int mp_lo = __builtin_amdgcn_readlane((int)(unsigned)mpb, 63);
    const int mp_hi = __builtin_amdgcn_readlane((int)(unsigned)(mpb >> 32), 63);
    const double mpd = u2d(((ull)(unsigned)mp_hi << 32) | (unsigned)mp_lo);

    // -- relax compute (waits on struct data) --
    const float g2full = __uint_as_float(sv.x) + __uint_as_float(sv.y);
    const float g2h = 0.5f * g2full; // exact scaling
    const unsigned f = nv.w;
    bool updv = false;
    ull pk = 0ull;
    if (relaxer) {
      updv = (f & 1u) &&
             (((f & 6u) == 0u) ||
              (((f & 2u) != 0u) && (__uint_as_float(nv.x) > g2full)));
      if (updv)
        pk = d2u((double)keyhalf(g2h, __uint_as_float(nv.z))) | (ull)(1023 - n);
    }
    // patch the pop in the group keys
    ull gcp = gco;
    if (lane < 16 && (gp * 16 + lane) == sel) gcp = (ull)(1023 - sel);

    // -- writes (EARLY: drain during the fold; R1 lesson) --
    const bool wr = updv || (lane == 8);
    if (wr) {
      uint4 wv;
      wv.x = updv ? __float_as_uint(g2full) : sv.x;
      wv.y = updv ? nv.y : sv.y;
      wv.z = updv ? nv.z : sv.z;
      wv.w = updv ? (f | 2u) : 5u; // pop: free|hist
      cellT[updv ? skew(n) : sxsel] = wv;
      key2[updv ? n : sel] = updv ? pk : (ull)(1023 - sel);
    }
    if (updv) par[n] = (unsigned)sel;
    if (lane < 16) atomicMax(&level1[gp], gcp); // rebuild group max
    if (updv) atomicMax(&level1[n >> 4], pk);
    const ull stale_n = level1[lane]; // snapshot of level1(S_i), after writes

    // -- late fold: row 0 only (group keys @0..15, pk merged @0..7, MP all) --
    double ml = 0.0;
    if (lane < 16) ml = u2d(gcp);
    if (updv) ml = fmax(ml, u2d(pk));
    ml = fmax(ml, mpd);
    ml = dpp_fmax64<0x111>(ml); // row_shr:1
    ml = dpp_fmax64<0x112>(ml); // row_shr:2
    ml = dpp_fmax64<0x114>(ml); // row_shr:4
    ml = dpp_fmax64<0x118>(ml); // row_shr:8 -> lane15 = max(lanes 0..15)
    const int lo15 = __builtin_amdgcn_readlane((int)(unsigned)d2u(ml), 15);
    sel = 1023 - (lo15 & 1023);
    stale = stale_n;
    __builtin_amdgcn_wave_barrier();
  }
  if (reached && lane == 0) {
    cellT[skew(goal)].w |= 4u; // hist includes goal
  }
  __builtin_amdgcn_wave_barrier();

  // ---- fused backtrack (lane 0): mark path via par bit31 ----
  if (lane == 0) {
    const unsigned pv = par[goal];
    par[goal] = pv | 0x80000000u; // path starts as goal one-hot
    unsigned loc = pv & 1023u;
#pragma unroll 1
    for (int i = 0; i < HW; ++i) {
      const unsigned w = par[loc];
      if (w & 0x80000000u) break; // deterministic replay of marked cells
      par[loc] = w | 0x80000000u;
      loc = w & 1023u;
    }
  }
  __builtin_amdgcn_wave_barrier();

  // ---- epilogue: hist + path ----
#pragma unroll
  for (int q = 0; q < 4; ++q) {
    const int base = q * 256 + lane * 4;
    float4 hv, pv;
    hv.x = (cellT[skew(base + 0)].w & 4u) ? 1.0f : 0.0f;
    hv.y = (cellT[skew(base + 1)].w & 4u) ? 1.0f : 0.0f;
    hv.z = (cellT[skew(base + 2)].w & 4u) ? 1.0f : 0.0f;
    hv.w = (cellT[skew(base + 3)].w & 4u) ? 1.0f : 0.0f;
    pv.x = (par[base + 0] >> 31) ? 1.0f : 0.0f;
    pv.y = (par[base + 1] >> 31) ? 1.0f : 0.0f;
    pv.z = (par[base + 2] >> 31) ? 1.0f : 0.0f;
    pv.w = (par[base + 3] >> 31) ? 1.0f : 0.0f;
    *(float4*)(out + b * HW + base) = hv;
    *(float4*)(out + NB * HW + b * HW + base) = pv;
  }
}

extern "C" void kernel_launch(void* const* d_in, const int* in_sizes, int n_in,
                              void* d_out, int out_size, void* d_ws,
                              size_t ws_size, hipStream_t stream) {
  const float* cm = (const float*)d_in[0];
  const float* sm = (const float*)d_in[1];
  const float* gm = (const float*)d_in[2];
  const float* om = (const float*)d_in[3];
  float* out = (float*)d_out;
  hipLaunchKernelGGL(astar_fused, dim3(NB), dim3(64), 0, stream, cm, sm, gm,
                     om, out);
}

// Round 3
// 96.265 us; speedup vs baseline: 1.0263x; 1.0263x over previous
//
#include <hip/hip_runtime.h>
#include <math.h>

#define HW 1024
#define NB 16
#define TMAXS 1024

typedef unsigned long long ull;

__device__ __forceinline__ double u2d(ull u) {
  return __longlong_as_double((long long)u);
}
__device__ __forceinline__ ull d2u(double d) {
  return (ull)__double_as_longlong(d);
}

// key = exp(-(0.5*g + 0.5*h)/sqrt(32)) with pre-halved operands (validated
// bit-exact vs reference in rounds 0-2: same f32 op chain, contract off).
__device__ __forceinline__ float keyhalf(float gh, float hh) {
#pragma clang fp contract(off)
  const float INV = 0.17677669529663687f; // fl32(1/sqrt(32))
  return expf(-(gh + hh) * INV);
}

// Pack (f32 key bits : 32 | (1023-idx) : 10) as u64.  Lexicographic order
// (key, then 1023-idx) is BIT-IDENTICAL to the validated f64 packing
// (f32->f64 is monotone-injective; idx bits never overlap key bits in
// either form; tie sets = exact f32 bit equality in both).  The value
// reinterpreted as f64 is nonneg & non-NaN (key in [0,1] -> exp field
// <= 0x3F8), so u64 order == f64 order and the DPP fmax chain applies.
__device__ __forceinline__ ull packkey(float keyf, int idx) {
  return ((ull)__float_as_uint(keyf) << 32) | (ull)(1023 - idx);
}

// One DPP reduction stage on a packed value (nonnegative as f64; disabled
// source lanes contribute 0.0 = identity). Chain validated all rounds.
template <int CTRL>
__device__ __forceinline__ double dpp_fmax64(double x) {
  ull u = d2u(x);
  int lo = (int)(unsigned)u;
  int hi = (int)(unsigned)(u >> 32);
  int lo2 = __builtin_amdgcn_update_dpp(0, lo, CTRL, 0xF, 0xF, false);
  int hi2 = __builtin_amdgcn_update_dpp(0, hi, CTRL, 0xF, 0xF, false);
  double y = u2d(((ull)(unsigned)hi2 << 32) | (unsigned)lo2);
  return fmax(x, y);
}

// ---------------------------------------------------------------------------
// Fused per-batch A* + backtrack, one wave per batch, incremental
// hierarchical argmax (level1 group maxes, exact maintenance).
// R3 = revert to the validated R0 structure (separate arrays, single
// 6-stage fold, early writes — R1/R2's split fold + struct merge both
// regressed; counters show the loop is ~90% latency-stalled, so only
// critical-path latency cuts pay).  Deltas vs R0, all bit-exact:
//   - u64 bit-pack of keys (drops v_cvt_f64_f32 from the exp->fold path)
//   - pre-halved gch fields {g, cm, 0.5*(g+cm), 0.5*h_full} (drops 2 muls
//     between the neighbor read and expf; validated in R1/R2)
//   - scalar (SALU) neighbor-validity mask on the uniform sel (shortens
//     readlane -> ds_read issue; validated in R2)
// ---------------------------------------------------------------------------
extern "C" __global__ void __launch_bounds__(64) astar_fused(
    const float* __restrict__ cm_g, const float* __restrict__ sm_g,
    const float* __restrict__ gm_g, const float* __restrict__ om_g,
    float* __restrict__ out) {
#pragma clang fp contract(off)
  const int b = blockIdx.x;
  const int lane = threadIdx.x;

  __shared__ __align__(16) ull key2[HW];     // packed (f32keybits | 1023-idx)
  __shared__ __align__(16) float4 gch[HW];   // {g, cm, 0.5*(g+cm), 0.5*h_full}
  __shared__ __align__(16) unsigned flg[HW]; // bit0 free, bit1 open, bit2 hist
  __shared__ __align__(16) unsigned par[HW]; // parent | mark bit31
  __shared__ __align__(16) ull level1[64];   // per-16-cell-group max
  const float* gchf = (const float*)gch;

  const float* cm = cm_g + b * HW;
  const float* sm = sm_g + b * HW;
  const float* gm = gm_g + b * HW;
  const float* om = om_g + b * HW;

  // ---- init pass 1: vectorized loads, locate goal/start ----
  float4 c4[4], o4[4];
  int gi = -1, si = -1;
#pragma unroll
  for (int q = 0; q < 4; ++q) {
    const int base = q * 256 + lane * 4;
    c4[q] = *(const float4*)(cm + base);
    o4[q] = *(const float4*)(om + base);
    const float4 s4 = *(const float4*)(sm + base);
    const float4 g4 = *(const float4*)(gm + base);
    const float sv[4] = {s4.x, s4.y, s4.z, s4.w};
    const float gv[4] = {g4.x, g4.y, g4.z, g4.w};
#pragma unroll
    for (int j = 0; j < 4; ++j) {
      if (gv[j] > 0.5f) gi = base + j;
      if (sv[j] > 0.5f) si = base + j;
    }
  }
#pragma unroll
  for (int m = 32; m >= 1; m >>= 1) {
    const int og = __shfl_xor(gi, m, 64);
    const int os = __shfl_xor(si, m, 64);
    gi = (og > gi) ? og : gi;
    si = (os > si) ? os : si;
  }
  const int goal = __builtin_amdgcn_readfirstlane(gi);
  const int start = __builtin_amdgcn_readfirstlane(si);

  // ---- init pass 2: h (exact ref op order), state arrays, level1 ----
  level1[lane] = 0ull; // before the atomics below (same array: order kept)
  const float grf = (float)(goal >> 5), gcf = (float)(goal & 31);
#pragma unroll
  for (int q = 0; q < 4; ++q) {
    const int base = q * 256 + lane * 4;
    const float cv[4] = {c4[q].x, c4[q].y, c4[q].z, c4[q].w};
    const float ov[4] = {o4[q].x, o4[q].y, o4[q].z, o4[q].w};
    ull pk[4];
    unsigned fv[4];
#pragma unroll
    for (int j = 0; j < 4; ++j) {
      const int cell = base + j;
      const float rr = (float)(cell >> 5), cc = (float)(cell & 31);
      const float dr = fabsf(rr - grf), dc = fabsf(cc - gcf);
      const float h0 = (dr + dc) - fminf(dr, dc); // exact (small ints)
      const float euc = sqrtf(dr * dr + dc * dc); // exact radicand
      const float t1 = 0.001f * euc;              // contract off: no fma
      const float hh = h0 + t1;
      const float hf = hh + cv[j]; // h_full (h + cm), exact ref order
      const float hw = 0.5f * hf;  // exact scaling
      gch[cell] = make_float4(0.0f, cv[j], 0.5f * cv[j], hw);
      fv[j] = (ov[j] > 0.5f) ? 1u : 0u;
      pk[j] = (ull)(1023 - cell);
      if (cell == start) {
        fv[j] |= 2u; // open = start map
        pk[j] = packkey(keyhalf(0.0f, hw), cell);
      }
      atomicMax(&level1[cell >> 4], pk[j]);
    }
    *(uint4*)&flg[base] = make_uint4(fv[0], fv[1], fv[2], fv[3]);
    *(uint4*)&par[base] =
        make_uint4((unsigned)goal, (unsigned)goal, (unsigned)goal, (unsigned)goal);
    ulonglong2 k01, k23;
    k01.x = pk[0]; k01.y = pk[1];
    k23.x = pk[2]; k23.y = pk[3];
    *(ulonglong2*)&key2[base] = k01;
    *(ulonglong2*)&key2[base + 2] = k23;
  }
  __builtin_amdgcn_wave_barrier();
  ull stale = level1[lane]; // S_{-1} group maxes

  int dlt = 0;
  {
    const int k = (lane < 4) ? lane : lane + 1; // skip center
    dlt = (k / 3 - 1) * 32 + (k % 3 - 1);
  }

  int sel = start; // step-0 argmax: start is the only open cell
  bool reached = false;

#pragma unroll 1
  for (int step = 0; step < TMAXS; ++step) {
    if (sel == goal) { reached = true; break; }
    const int gp = sel >> 4;

    // scalar (SALU) neighbor-validity mask on uniform sel
    // lanes: 0,1,2 = top row; 0,3,5 = left col; 2,4,7 = right col;
    //        5,6,7 = bottom row
    const int sr = sel >> 5, sc = sel & 31;
    unsigned vmask = 0xFFu;
    if (sr == 0) vmask &= ~0x07u;
    if (sr == 31) vmask &= ~0xE0u;
    if (sc == 0) vmask &= ~0x29u;
    if (sc == 31) vmask &= ~0x94u;

    // -- DS phase 1: zero popped group's level1; issue all reads --
    if (lane == 8) level1[gp] = 0ull;
    const float g2h = gchf[4 * sel + 2]; // broadcast: 0.5*(g[sel]+cm[sel])
    int n = -1;
    if (lane < 8) {
      if ((vmask >> lane) & 1u) n = sel + dlt;
    } else if (lane == 8) {
      n = sel;
    }
    unsigned f = 0;
    if (n >= 0) f = flg[n];
    float4 v = make_float4(0.f, 0.f, 0.f, 0.f);
    if (lane < 8 && n >= 0) v = gch[n];
    ull gc = 0ull;
    const bool grpLane = (lane >= 32) && (lane < 48);
    if (grpLane) {
      const int gcell = gp * 16 + (lane - 32);
      gc = key2[gcell];
      if (gcell == sel) gc = (ull)(1023 - sel); // patch the pop
      atomicMax(&level1[gp], gc);               // rebuild group max
    }

    // -- relax compute + writes + level1 maintenance --
    const float g2full = g2h + g2h; // exact: 2*(0.5*x) == x
    bool updv = false;
    ull pk = 0ull;
    if (lane < 8 && n >= 0) {
      updv = (f & 1u) && (((f & 6u) == 0u) || (((f & 2u) != 0u) && (v.x > g2full)));
      if (updv) pk = packkey(keyhalf(g2h, v.w), n);
    }
    if (updv) {
      gch[n] = make_float4(g2full, v.y, 0.5f * (g2full + v.y), v.w);
      par[n] = (unsigned)sel;
    }
    if (updv || lane == 8) {
      flg[n] = (lane == 8) ? ((f | 4u) & ~2u) : (f | 2u);
      key2[n] = (lane == 8) ? (ull)(1023 - sel) : pk;
    }
    if (updv) atomicMax(&level1[n >> 4], pk);

    // -- reduce over S_i: stale (gp zeroed) + group folds + ring folds --
    double m = (lane == gp) ? 0.0 : u2d(stale);
    if (grpLane) m = fmax(m, u2d(gc));
    if (updv) m = fmax(m, u2d(pk));
    m = dpp_fmax64<0x111>(m); // row_shr:1
    m = dpp_fmax64<0x112>(m); // row_shr:2
    m = dpp_fmax64<0x114>(m); // row_shr:4
    m = dpp_fmax64<0x118>(m); // row_shr:8
    m = dpp_fmax64<0x142>(m); // row_bcast:15
    m = dpp_fmax64<0x143>(m); // row_bcast:31

    // -- stale snapshot of level1(S_i) for next iter (after all writes) --
    stale = level1[lane];

    const int lo63 = __builtin_amdgcn_readlane((int)(unsigned)d2u(m), 63);
    sel = 1023 - (lo63 & 1023);
    __builtin_amdgcn_wave_barrier();
  }
  if (reached && lane == 0) flg[goal] |= 4u; // hist includes goal
  __builtin_amdgcn_wave_barrier();

  // ---- fused backtrack (lane 0): mark path via par bit31 ----
  if (lane == 0) {
    const unsigned pv = par[goal];
    par[goal] = pv | 0x80000000u; // path starts as goal one-hot
    unsigned loc = pv & 1023u;
#pragma unroll 1
    for (int i = 0; i < HW; ++i) {
      const unsigned w = par[loc];
      if (w & 0x80000000u) break; // deterministic replay of marked cells
      par[loc] = w | 0x80000000u;
      loc = w & 1023u;
    }
  }
  __builtin_amdgcn_wave_barrier();

  // ---- epilogue: hist + path ----
#pragma unroll
  for (int q = 0; q < 4; ++q) {
    const int base = q * 256 + lane * 4;
    float4 hv, pv;
    hv.x = (flg[base + 0] & 4u) ? 1.0f : 0.0f;
    hv.y = (flg[base + 1] & 4u) ? 1.0f : 0.0f;
    hv.z = (flg[base + 2] & 4u) ? 1.0f : 0.0f;
    hv.w = (flg[base + 3] & 4u) ? 1.0f : 0.0f;
    pv.x = (par[base + 0] >> 31) ? 1.0f : 0.0f;
    pv.y = (par[base + 1] >> 31) ? 1.0f : 0.0f;
    pv.z = (par[base + 2] >> 31) ? 1.0f : 0.0f;
    pv.w = (par[base + 3] >> 31) ? 1.0f : 0.0f;
    *(float4*)(out + b * HW + base) = hv;
    *(float4*)(out + NB * HW + b * HW + base) = pv;
  }
}

extern "C" void kernel_launch(void* const* d_in, const int* in_sizes, int n_in,
                              void* d_out, int out_size, void* d_ws,
                              size_t ws_size, hipStream_t stream) {
  const float* cm = (const float*)d_in[0];
  const float* sm = (const float*)d_in[1];
  const float* gm = (const float*)d_in[2];
  const float* om = (const float*)d_in[3];
  float* out = (float*)d_out;
  hipLaunchKernelGGL(astar_fused, dim3(NB), dim3(64), 0, stream, cm, sm, gm,
                     om, out);
}

// Round 4
// 76.485 us; speedup vs baseline: 1.2917x; 1.2586x over previous
//
#include <hip/hip_runtime.h>
#include <math.h>

#define HW 1024
#define NB 16
#define TMAXS 1024

typedef unsigned long long ull;

__device__ __forceinline__ double u2d(ull u) {
  return __longlong_as_double((long long)u);
}
__device__ __forceinline__ ull d2u(double d) {
  return (ull)__double_as_longlong(d);
}

// key = exp(-(0.5*g + 0.5*h)/sqrt(32)) with pre-halved operands (validated
// bit-exact vs reference rounds 0-3: same f32 op chain, contract off).
__device__ __forceinline__ float keyhalf(float gh, float hh) {
#pragma clang fp contract(off)
  const float INV = 0.17677669529663687f; // fl32(1/sqrt(32))
  return expf(-(gh + hh) * INV);
}

// (f32 key bits : 32 | (1023-idx) : 10) as u64 — order & ties bit-identical
// to the validated f64 packing; reinterpreted as f64 it is nonneg/non-NaN
// (key in [0,1] -> exp field <= 0x3F8), so the fmax DPP chain applies.
__device__ __forceinline__ ull packkey(float keyf, int idx) {
  return ((ull)__float_as_uint(keyf) << 32) | (ull)(1023 - idx);
}

// One DPP reduction stage on a packed value (nonnegative as f64; disabled
// source lanes contribute 0.0 = identity). Chain validated all rounds.
template <int CTRL>
__device__ __forceinline__ double dpp_fmax64(double x) {
  ull u = d2u(x);
  int lo = (int)(unsigned)u;
  int hi = (int)(unsigned)(u >> 32);
  int lo2 = __builtin_amdgcn_update_dpp(0, lo, CTRL, 0xF, 0xF, false);
  int hi2 = __builtin_amdgcn_update_dpp(0, hi, CTRL, 0xF, 0xF, false);
  double y = u2d(((ull)(unsigned)hi2 << 32) | (unsigned)lo2);
  return fmax(x, y);
}

// ---------------------------------------------------------------------------
// Fused per-batch A* + backtrack, one wave per batch.
// R4: split-argmax restructure. The argmax over the multiset
//   M = stale'(64, register) ∪ gc(16, group rebuild) ∪ pk(<=8, fresh relax)
// is decomposed (max associative; packed idx ties unchanged => identical
// winner) into:
//   A: 6-stage DPP fold over stale' (register-only -> hides under LDS wait)
//   B,C: pk on lanes 0..7, patched group keys on lanes 16..31 -> ONE shared
//        4-stage row fold (DPP row ops don't cross 16-lane rows) -> lane15 =
//        max pk, lane31 = max gc.  Lane31's value IS the rebuilt group max,
//        stored directly to level1[gp] (replaces zero-store + 16 atomics).
//   final: 6 readlanes + scalar u64 max3 -> sel.
// DS diet (all individually validated / bit-exact):
//   - cell struct uint4 {g, cm, hw=0.5*h_full, flg}: one b128 neighbor read
//     (replaces flg b32 + gch b128), one b128 relax write.
//   - pop: b64 broadcast {g, cm}; g2full = g+cm recomputed (same operands,
//     same single add as ref => bit-identical); flg write = constant 5
//     (popped cell is open & free & !hist — invariant validated in R2).
// DS order per iter: reads(cell[sel] b64, cell[n] b128, key2 group) ->
//   writes(cell/par/key2) -> level1[gp] store -> relax atomicMax -> stale
//   read.  Same-array program order gives all the hazard guarantees of the
//   validated rounds (reads-before-writes; level1 store before pk atomic;
//   stale last).
// ---------------------------------------------------------------------------
extern "C" __global__ void __launch_bounds__(64) astar_fused(
    const float* __restrict__ cm_g, const float* __restrict__ sm_g,
    const float* __restrict__ gm_g, const float* __restrict__ om_g,
    float* __restrict__ out) {
#pragma clang fp contract(off)
  const int b = blockIdx.x;
  const int lane = threadIdx.x;

  __shared__ __align__(16) uint4 cellT[HW];  // {g, cm, hw, flg}
  __shared__ __align__(16) ull key2[HW];     // packed (f32keybits | 1023-idx)
  __shared__ __align__(16) unsigned par[HW]; // parent | mark bit31
  __shared__ __align__(16) ull level1[64];   // per-16-cell-group max
  const float2* cell2 = (const float2*)cellT; // {g, cm} pairs (stride 2)
  unsigned* cellu = (unsigned*)cellT;

  const float* cm = cm_g + b * HW;
  const float* sm = sm_g + b * HW;
  const float* gm = gm_g + b * HW;
  const float* om = om_g + b * HW;

  // ---- init pass 1: vectorized loads, locate goal/start ----
  float4 c4[4], o4[4];
  int gi = -1, si = -1;
#pragma unroll
  for (int q = 0; q < 4; ++q) {
    const int base = q * 256 + lane * 4;
    c4[q] = *(const float4*)(cm + base);
    o4[q] = *(const float4*)(om + base);
    const float4 s4 = *(const float4*)(sm + base);
    const float4 g4 = *(const float4*)(gm + base);
    const float sv[4] = {s4.x, s4.y, s4.z, s4.w};
    const float gv[4] = {g4.x, g4.y, g4.z, g4.w};
#pragma unroll
    for (int j = 0; j < 4; ++j) {
      if (gv[j] > 0.5f) gi = base + j;
      if (sv[j] > 0.5f) si = base + j;
    }
  }
#pragma unroll
  for (int m = 32; m >= 1; m >>= 1) {
    const int og = __shfl_xor(gi, m, 64);
    const int os = __shfl_xor(si, m, 64);
    gi = (og > gi) ? og : gi;
    si = (os > si) ? os : si;
  }
  const int goal = __builtin_amdgcn_readfirstlane(gi);
  const int start = __builtin_amdgcn_readfirstlane(si);

  // ---- init pass 2: h (exact ref op order), cell structs, key2, level1 ----
  level1[lane] = 0ull; // before the atomics below (same array: order kept)
  const float grf = (float)(goal >> 5), gcf = (float)(goal & 31);
#pragma unroll
  for (int q = 0; q < 4; ++q) {
    const int base = q * 256 + lane * 4;
    const float cv[4] = {c4[q].x, c4[q].y, c4[q].z, c4[q].w};
    const float ov[4] = {o4[q].x, o4[q].y, o4[q].z, o4[q].w};
    ull pk[4];
#pragma unroll
    for (int j = 0; j < 4; ++j) {
      const int cell = base + j;
      const float rr = (float)(cell >> 5), cc = (float)(cell & 31);
      const float dr = fabsf(rr - grf), dc = fabsf(cc - gcf);
      const float h0 = (dr + dc) - fminf(dr, dc); // exact (small ints)
      const float euc = sqrtf(dr * dr + dc * dc); // exact radicand
      const float t1 = 0.001f * euc;              // contract off: no fma
      const float hh = h0 + t1;
      const float hf = hh + cv[j]; // h_full (h + cm), exact ref order
      const float hw = 0.5f * hf;  // exact scaling
      unsigned fv = (ov[j] > 0.5f) ? 1u : 0u;
      pk[j] = (ull)(1023 - cell);
      if (cell == start) {
        fv |= 2u; // open = start map
        pk[j] = packkey(keyhalf(0.0f, hw), cell);
      }
      cellT[cell] = make_uint4(__float_as_uint(0.0f), __float_as_uint(cv[j]),
                               __float_as_uint(hw), fv);
      atomicMax(&level1[cell >> 4], pk[j]);
    }
    *(uint4*)&par[base] =
        make_uint4((unsigned)goal, (unsigned)goal, (unsigned)goal, (unsigned)goal);
    ulonglong2 k01, k23;
    k01.x = pk[0]; k01.y = pk[1];
    k23.x = pk[2]; k23.y = pk[3];
    *(ulonglong2*)&key2[base] = k01;
    *(ulonglong2*)&key2[base + 2] = k23;
  }
  __builtin_amdgcn_wave_barrier();
  ull stale = level1[lane]; // S_{-1} group maxes

  int dlt = 0;
  if (lane < 8) {
    const int k = (lane < 4) ? lane : lane + 1; // skip center
    dlt = (k / 3 - 1) * 32 + (k % 3 - 1);
  }

  int sel = start; // step-0 argmax: start is the only open cell
  bool reached = false;

#pragma unroll 1
  for (int step = 0; step < TMAXS; ++step) {
    if (sel == goal) { reached = true; break; }
    const int gp = sel >> 4;

    // scalar (SALU) neighbor-validity mask on uniform sel
    // lanes: 0,1,2 = top row; 0,3,5 = left col; 2,4,7 = right col;
    //        5,6,7 = bottom row
    const int sr = sel >> 5, sc = sel & 31;
    unsigned vmask = 0xFFu;
    if (sr == 0) vmask &= ~0x07u;
    if (sr == 31) vmask &= ~0xE0u;
    if (sc == 0) vmask &= ~0x29u;
    if (sc == 31) vmask &= ~0x94u;

    // -- issue all LDS reads first --
    const float2 sg = cell2[2 * sel]; // broadcast {g[sel], cm[sel]}
    const int n = sel + dlt;
    const bool relaxer = (lane < 8) && ((vmask >> lane) & 1u);
    uint4 nv = make_uint4(0u, 0u, 0u, 0u);
    if (relaxer) nv = cellT[n];
    const bool gcl = (lane >= 16) && (lane < 32);
    const int gcell = gp * 16 + (lane - 16);
    ull gco = 0ull;
    if (gcl) gco = key2[gcell];

    // -- chain A: 6-stage fold over stale' (register-only; hides under the
    //    LDS latency window) --
    double ma = (lane == gp) ? 0.0 : u2d(stale);
    ma = dpp_fmax64<0x111>(ma); // row_shr:1
    ma = dpp_fmax64<0x112>(ma); // row_shr:2
    ma = dpp_fmax64<0x114>(ma); // row_shr:4
    ma = dpp_fmax64<0x118>(ma); // row_shr:8
    ma = dpp_fmax64<0x142>(ma); // row_bcast:15
    ma = dpp_fmax64<0x143>(ma); // row_bcast:31 -> lane63 = max(all)

    // -- relax compute (waits on broadcast + neighbor struct) --
    const float g2full = sg.x + sg.y;  // g[sel] + cm[sel], exact ref order
    const float g2h = 0.5f * g2full;   // exact scaling
    const unsigned f = nv.w;
    bool updv = false;
    ull pk = 0ull;
    if (relaxer) {
      updv = (f & 1u) &&
             (((f & 6u) == 0u) ||
              (((f & 2u) != 0u) && (__uint_as_float(nv.x) > g2full)));
      if (updv) pk = packkey(keyhalf(g2h, __uint_as_float(nv.z)), n);
    }
    // patch the pop in the group keys
    ull gcp = gco;
    if (gcl && gcell == sel) gcp = (ull)(1023 - sel);

    // -- early writes (drain during the fold; R1 lesson). Reads above
    //    precede these in DS program order. --
    if (updv) {
      cellT[n] = make_uint4(__float_as_uint(g2full), nv.y, nv.z, f | 2u);
      par[n] = (unsigned)sel;
      key2[n] = pk;
    }
    if (lane == 8) {
      cellu[4 * sel + 3] = 5u;          // pop: free|hist (validated const)
      key2[sel] = (ull)(1023 - sel);    // denormal entry
    }

    // -- chains B,C: shared 4-stage row fold (rows don't leak) --
    double ml = 0.0;
    if (gcl) ml = u2d(gcp);
    if (updv) ml = u2d(pk);
    ml = dpp_fmax64<0x111>(ml); // row_shr:1
    ml = dpp_fmax64<0x112>(ml); // row_shr:2
    ml = dpp_fmax64<0x114>(ml); // row_shr:4
    ml = dpp_fmax64<0x118>(ml); // row_shr:8
    // lane15 = max pk (lanes 0..7), lane31 = max gcp (lanes 16..31)

    // -- level1 maintenance: rebuilt group max from the fold itself, then
    //    relax atomics, then stale snapshot (same-array order) --
    if (lane == 31) level1[gp] = d2u(ml);
    if (updv) atomicMax(&level1[n >> 4], pk);
    const ull stale_n = level1[lane];

    // -- readlanes + scalar u64 max3 (== nonneg-f64 order, same ties) --
    const ull mlb = d2u(ml);
    const ull mab = d2u(ma);
    const int b_lo = __builtin_amdgcn_readlane((int)(unsigned)mlb, 15);
    const int b_hi = __builtin_amdgcn_readlane((int)(unsigned)(mlb >> 32), 15);
    const int c_lo = __builtin_amdgcn_readlane((int)(unsigned)mlb, 31);
    const int c_hi = __builtin_amdgcn_readlane((int)(unsigned)(mlb >> 32), 31);
    const int a_lo = __builtin_amdgcn_readlane((int)(unsigned)mab, 63);
    const int a_hi = __builtin_amdgcn_readlane((int)(unsigned)(mab >> 32), 63);
    const ull B2 = ((ull)(unsigned)b_hi << 32) | (unsigned)b_lo;
    const ull C2 = ((ull)(unsigned)c_hi << 32) | (unsigned)c_lo;
    const ull A2 = ((ull)(unsigned)a_hi << 32) | (unsigned)a_lo;
    ull M = (B2 > C2) ? B2 : C2;
    M = (M > A2) ? M : A2;
    sel = 1023 - (int)((unsigned)M & 1023u);
    stale = stale_n;
    __builtin_amdgcn_wave_barrier();
  }
  if (reached && lane == 0) cellu[4 * goal + 3] |= 4u; // hist includes goal
  __builtin_amdgcn_wave_barrier();

  // ---- fused backtrack (lane 0): mark path via par bit31 ----
  if (lane == 0) {
    const unsigned pv = par[goal];
    par[goal] = pv | 0x80000000u; // path starts as goal one-hot
    unsigned loc = pv & 1023u;
#pragma unroll 1
    for (int i = 0; i < HW; ++i) {
      const unsigned w = par[loc];
      if (w & 0x80000000u) break; // deterministic replay of marked cells
      par[loc] = w | 0x80000000u;
      loc = w & 1023u;
    }
  }
  __builtin_amdgcn_wave_barrier();

  // ---- epilogue: hist + path ----
#pragma unroll
  for (int q = 0; q < 4; ++q) {
    const int base = q * 256 + lane * 4;
    float4 hv, pv;
    hv.x = (cellu[4 * (base + 0) + 3] & 4u) ? 1.0f : 0.0f;
    hv.y = (cellu[4 * (base + 1) + 3] & 4u) ? 1.0f : 0.0f;
    hv.z = (cellu[4 * (base + 2) + 3] & 4u) ? 1.0f : 0.0f;
    hv.w = (cellu[4 * (base + 3) + 3] & 4u) ? 1.0f : 0.0f;
    pv.x = (par[base + 0] >> 31) ? 1.0f : 0.0f;
    pv.y = (par[base + 1] >> 31) ? 1.0f : 0.0f;
    pv.z = (par[base + 2] >> 31) ? 1.0f : 0.0f;
    pv.w = (par[base + 3] >> 31) ? 1.0f : 0.0f;
    *(float4*)(out + b * HW + base) = hv;
    *(float4*)(out + NB * HW + b * HW + base) = pv;
  }
}

extern "C" void kernel_launch(void* const* d_in, const int* in_sizes, int n_in,
                              void* d_out, int out_size, void* d_ws,
                              size_t ws_size, hipStream_t stream) {
  const float* cm = (const float*)d_in[0];
  const float* sm = (const float*)d_in[1];
  const float* gm = (const float*)d_in[2];
  const float* om = (const float*)d_in[3];
  float* out = (float*)d_out;
  hipLaunchKernelGGL(astar_fused, dim3(NB), dim3(64), 0, stream, cm, sm, gm,
                     om, out);
}